// Round 4
// baseline (1162.523 us; speedup 1.0000x reference)
//
#include <hip/hip_runtime.h>

// Problem constants
constexpr int L = 4, D = 512, H = 8, DFF = 2048, NSEQ = 512, B = 16, C = 3;
constexpr int DH = D / H;          // 64
constexpr int M = B * NSEQ;        // 8192 tokens
constexpr int BND = B * NSEQ * D;  // 4,194,304

typedef short bf16x8 __attribute__((ext_vector_type(8)));
typedef float f32x4 __attribute__((ext_vector_type(4)));

// bf16 helpers (OCP bf16 = top 16 bits of fp32)
__device__ __forceinline__ float blo(unsigned u) { return __uint_as_float(u << 16); }
__device__ __forceinline__ float bhi(unsigned u) { return __uint_as_float(u & 0xffff0000u); }
__device__ __forceinline__ unsigned short f2b(float f) {   // RNE
    unsigned u = __float_as_uint(f);
    u += 0x7fffu + ((u >> 16) & 1u);
    return (unsigned short)(u >> 16);
}
__device__ __forceinline__ void gload_lds16(const void* g, void* l) {
    __builtin_amdgcn_global_load_lds(
        (const __attribute__((address_space(1))) void*)g,
        (__attribute__((address_space(3))) void*)l, 16, 0, 0);
}

__device__ __forceinline__ float block_sum256(float v, float* r4) {
#pragma unroll
    for (int o = 32; o > 0; o >>= 1) v += __shfl_xor(v, o, 64);
    if ((threadIdx.x & 63) == 0) r4[threadIdx.x >> 6] = v;
    __syncthreads();
    return r4[0] + r4[1] + r4[2] + r4[3];
}

// ---------------------------------------------------------------------------
// 0. Weight convert + transpose: in fp32 [K][N] -> out bf16 [N][K].
//    grid.z = L; per-layer output stride lstride (shorts).
__global__ __launch_bounds__(256) void conv_t_kernel(
    const float* __restrict__ in, unsigned short* __restrict__ out,
    int K, int N, int lstride)
{
    __shared__ float t[32][33];
    int n0 = blockIdx.x * 32, k0 = blockIdx.y * 32;
    const float* ip = in + (size_t)blockIdx.z * K * N;
    unsigned short* op = out + (size_t)blockIdx.z * lstride;
    int tx = threadIdx.x & 31, ty = threadIdx.x >> 5;   // 32 x 8
#pragma unroll
    for (int i = 0; i < 4; i++)
        t[ty + i * 8][tx] = ip[(size_t)(k0 + ty + i * 8) * N + n0 + tx];
    __syncthreads();
#pragma unroll
    for (int i = 0; i < 4; i++)
        op[(size_t)(n0 + ty + i * 8) * K + k0 + tx] = f2b(t[tx][ty + i * 8]);
}

// ---------------------------------------------------------------------------
// 1. Embedding * sqrt(D) + sinusoidal PE.  x[b,n,d] fp32.
__global__ __launch_bounds__(256) void embed_pe_kernel(
    const int* __restrict__ src, const float* __restrict__ emb,
    float* __restrict__ x)
{
    int idx = blockIdx.x * 256 + threadIdx.x;   // over B*N*D
    int d = idx & (D - 1);
    int t = idx >> 9;            // b*N + n
    int n = t & (NSEQ - 1);
    int b = t >> 9;
    int tok = src[n * B + b];
    float e = emb[(size_t)tok * D + d] * 22.627416997969522f;  // sqrt(512)
    float div = expf((float)(d & ~1) * -0.01798894603797866f); // -ln(1e4)/512
    float ang = (float)n * div;
    float pe = (d & 1) ? cosf(ang) : sinf(ang);
    x[idx] = e + pe;
}

// ---------------------------------------------------------------------------
// 2. LayerNorm over D=512, one block (256 thr) per row. Optional bf16 output.
template<int BF16OUT>
__global__ __launch_bounds__(256) void ln_kernel(
    const float* __restrict__ in, const float* __restrict__ g,
    const float* __restrict__ bt, void* __restrict__ outv)
{
    __shared__ float ra[4], rb[4];
    int row = blockIdx.x, tid = threadIdx.x;
    const float* p = in + (size_t)row * D;
    float v0 = p[tid], v1 = p[tid + 256];
    float mean = block_sum256(v0 + v1, ra) * (1.0f / D);
    float d0 = v0 - mean, d1 = v1 - mean;
    float var = block_sum256(d0 * d0 + d1 * d1, rb) * (1.0f / D);
    float rstd = rsqrtf(var + 1e-6f);
    float o0 = d0 * rstd * g[tid] + bt[tid];
    float o1 = d1 * rstd * g[tid + 256] + bt[tid + 256];
    if (BF16OUT) {
        unsigned short* o = (unsigned short*)outv + (size_t)row * D;
        o[tid] = f2b(o0); o[tid + 256] = f2b(o1);
    } else {
        float* o = (float*)outv + (size_t)row * D;
        o[tid] = o0; o[tid + 256] = o1;
    }
}

// ---------------------------------------------------------------------------
// 3. bf16 MFMA GEMM (m97 structure): 128x128 tile, BK=32, 4 waves.
//    EPI: 0 = fp32 add into out0 (atomicAdd if SPLITK>1; bias only at kz==0)
//         1 = bf16 store             2 = bf16 relu store
//         3 = fused QKV routing: Q->out0, K->out1, V^T->out2 (all bf16)
//    SPLITK: blockIdx.z slices K into contiguous chunks.
template<int EPI, int SPLITK>
__global__ __launch_bounds__(256) void mfma_gemm(
    const unsigned short* __restrict__ A,    // [Mrows][Kdim] bf16
    const unsigned short* __restrict__ Wt,   // [Ndim][Kdim] bf16 (pre-transposed)
    const float* __restrict__ biasQ, const float* __restrict__ biasK,
    const float* __restrict__ biasV,
    void* __restrict__ out0, void* __restrict__ out1, void* __restrict__ out2,
    int Kdim, int Ndim)
{
    __shared__ __align__(16) unsigned short As[128 * 32];  // [m][k]
    __shared__ __align__(16) unsigned short Bs[128 * 32];  // [n][k]
    int tid = threadIdx.x;
    int wave = tid >> 6, lane = tid & 63;
    int lr = lane & 15, lc = lane >> 4;      // frag row(m/n), k-group
    int m0 = blockIdx.y * 128, n0 = blockIdx.x * 128;
    int kz = blockIdx.z;
    int wm = (wave >> 1) * 64, wn = (wave & 1) * 64;
    int srow = tid >> 2;                     // staging: row within 64-row chunk
    int scol = (tid & 3) << 3;               // staging: k offset (8 bf16 = 16B)

    const unsigned short* Ab = A + ((size_t)m0 + srow) * Kdim + scol;
    const unsigned short* Bb = Wt + ((size_t)n0 + srow) * Kdim + scol;
    unsigned short* AsW = As + wave * 512;   // wave-uniform LDS dest
    unsigned short* BsW = Bs + wave * 512;

    int kpart = Kdim / SPLITK;
    int kbeg = kz * kpart, kend = kbeg + kpart;

    f32x4 acc[4][4] = {};

    for (int kb = kbeg; kb < kend; kb += 32) {
        gload_lds16(Ab + kb, AsW);                               // rows 0-63
        gload_lds16(Ab + kb + (size_t)64 * Kdim, AsW + 2048);    // rows 64-127
        gload_lds16(Bb + kb, BsW);
        gload_lds16(Bb + kb + (size_t)64 * Kdim, BsW + 2048);
        __syncthreads();   // compiler drains vmcnt(0) before s_barrier

        bf16x8 aF[4], bF[4];
#pragma unroll
        for (int i = 0; i < 4; i++) {
            aF[i] = *reinterpret_cast<const bf16x8*>(&As[(wm + i * 16 + lr) * 32 + lc * 8]);
            bF[i] = *reinterpret_cast<const bf16x8*>(&Bs[(wn + i * 16 + lr) * 32 + lc * 8]);
        }
#pragma unroll
        for (int i = 0; i < 4; i++)
#pragma unroll
            for (int j = 0; j < 4; j++)
                acc[i][j] = __builtin_amdgcn_mfma_f32_16x16x32_bf16(aF[i], bF[j], acc[i][j], 0, 0, 0);
        __syncthreads();
    }

    // epilogue: C row = (lane>>4)*4 + r, col = lane&15  (m89-verified layout)
#pragma unroll
    for (int i = 0; i < 4; i++) {
        int grow = m0 + wm + i * 16 + lc * 4;
#pragma unroll
        for (int j = 0; j < 4; j++) {
            int gcol = n0 + wn + j * 16 + lr;
            float bv;
            if (EPI == 3)
                bv = (gcol < D) ? biasQ[gcol]
                   : (gcol < 2 * D) ? biasK[gcol - D] : biasV[gcol - 2 * D];
            else
                bv = (EPI == 0 && kz != 0) ? 0.0f : biasQ[gcol];
#pragma unroll
            for (int r = 0; r < 4; r++) {
                float v = acc[i][j][r] + bv;
                if (EPI == 2) v = fmaxf(v, 0.0f);
                int tok = grow + r;
                if (EPI == 0) {
                    float* op = (float*)out0 + (size_t)tok * Ndim + gcol;
                    if (SPLITK > 1) atomicAdd(op, v); else *op += v;
                } else if (EPI == 3) {
                    if (gcol < D)
                        ((unsigned short*)out0)[(size_t)tok * D + gcol] = f2b(v);
                    else if (gcol < 2 * D)
                        ((unsigned short*)out1)[(size_t)tok * D + gcol - D] = f2b(v);
                    else {
                        int dcol = gcol - 2 * D;   // V^T: [(b*512 + dcol)][n]
                        ((unsigned short*)out2)[
                            (((size_t)(tok >> 9) << 9) + dcol) * NSEQ + (tok & (NSEQ - 1))] = f2b(v);
                    }
                } else {
                    ((unsigned short*)out0)[(size_t)tok * Ndim + gcol] = f2b(v);
                }
            }
        }
    }
}

// ---------------------------------------------------------------------------
// 4. Flash attention, MFMA core. bf16 Q/K/V^T in, bf16 ctx out.
//    One block per (b, h, 64-q-tile); 4 waves, each owns a 16-row q-strip.
__global__ __launch_bounds__(256, 3) void attn_mfma_kernel(
    const unsigned short* __restrict__ qg, const unsigned short* __restrict__ kg,
    const unsigned short* __restrict__ vtg, const int* __restrict__ lengths,
    unsigned short* __restrict__ ctx)
{
    __shared__ __align__(16) unsigned short Ks[64 * 64];  // [kv][d] swizzled
    __shared__ __align__(16) unsigned short Vt[64 * 64];  // [d][kv] swizzled
    __shared__ __align__(16) unsigned short Ps[64 * 64];  // Q staging, then P [q][kv]

    int tid = threadIdx.x;
    int wave = tid >> 6, lane = tid & 63;
    int lr = lane & 15, lc = lane >> 4;
    int qt = blockIdx.x, hh = blockIdx.y, b = blockIdx.z;
    int len = lengths[b];

    const unsigned short* qbase  = qg  + ((size_t)(b * NSEQ + qt * 64)) * D + hh * DH;
    const unsigned short* kbase  = kg  + ((size_t)(b * NSEQ)) * D + hh * DH;
    const unsigned short* vtbase = vtg + ((size_t)(b * D + hh * DH)) * NSEQ;

    auto SW = [](int row, int colbyte) { return row * 128 + (colbyte ^ ((row & 7) << 4)); };

#pragma unroll
    for (int it = 0; it < 2; it++) {
        int c = it * 256 + tid;
        int row = c >> 3, d0 = (c & 7) << 3;
        uint4 t = *reinterpret_cast<const uint4*>(qbase + (size_t)row * D + d0);
        *reinterpret_cast<uint4*>((char*)Ps + SW(row, d0 * 2)) = t;
    }
    __syncthreads();
    bf16x8 aQ[2];
#pragma unroll
    for (int s = 0; s < 2; s++)
        aQ[s] = *reinterpret_cast<const bf16x8*>((char*)Ps + SW(wave * 16 + lr, s * 64 + lc * 16));

    f32x4 o[4] = {};
    float mrow[4], lrow[4];
#pragma unroll
    for (int r = 0; r < 4; r++) { mrow[r] = -INFINITY; lrow[r] = 0.0f; }

    for (int kt = 0; kt < 8; kt++) {
#pragma unroll
        for (int it = 0; it < 2; it++) {
            int c = it * 256 + tid;
            int row = c >> 3, d0 = (c & 7) << 3;
            uint4 t = *reinterpret_cast<const uint4*>(kbase + (size_t)(kt * 64 + row) * D + d0);
            *reinterpret_cast<uint4*>((char*)Ks + SW(row, d0 * 2)) = t;
            uint4 tv = *reinterpret_cast<const uint4*>(vtbase + (size_t)row * NSEQ + kt * 64 + d0);
            *reinterpret_cast<uint4*>((char*)Vt + SW(row, d0 * 2)) = tv;
        }
        __syncthreads();

        f32x4 sacc[4] = {};
#pragma unroll
        for (int kf = 0; kf < 4; kf++) {
#pragma unroll
            for (int s = 0; s < 2; s++) {
                bf16x8 bK = *reinterpret_cast<const bf16x8*>((char*)Ks + SW(kf * 16 + lr, s * 64 + lc * 16));
                sacc[kf] = __builtin_amdgcn_mfma_f32_16x16x32_bf16(aQ[s], bK, sacc[kf], 0, 0, 0);
            }
        }

        float p[4][4], tm[4];
#pragma unroll
        for (int r = 0; r < 4; r++) tm[r] = -INFINITY;
#pragma unroll
        for (int kf = 0; kf < 4; kf++) {
            int col = kt * 64 + kf * 16 + lr;
            bool ok = col < len;
#pragma unroll
            for (int r = 0; r < 4; r++) {
                float sv = ok ? sacc[kf][r] * 0.125f : -1e9f;
                p[kf][r] = sv;
                tm[r] = fmaxf(tm[r], sv);
            }
        }
#pragma unroll
        for (int r = 0; r < 4; r++) {
#pragma unroll
            for (int msk = 1; msk < 16; msk <<= 1)
                tm[r] = fmaxf(tm[r], __shfl_xor(tm[r], msk, 64));
        }
        float alpha[4], ps[4];
#pragma unroll
        for (int r = 0; r < 4; r++) {
            float nm = fmaxf(mrow[r], tm[r]);
            alpha[r] = __expf(mrow[r] - nm);
            mrow[r] = nm;
            ps[r] = 0.0f;
        }
#pragma unroll
        for (int kf = 0; kf < 4; kf++)
#pragma unroll
            for (int r = 0; r < 4; r++) {
                float e = __expf(p[kf][r] - mrow[r]);
                p[kf][r] = e;
                ps[r] += e;
            }
#pragma unroll
        for (int r = 0; r < 4; r++) {
#pragma unroll
            for (int msk = 1; msk < 16; msk <<= 1)
                ps[r] += __shfl_xor(ps[r], msk, 64);
            lrow[r] = lrow[r] * alpha[r] + ps[r];
        }

#pragma unroll
        for (int kf = 0; kf < 4; kf++)
#pragma unroll
            for (int r = 0; r < 4; r++)
                *reinterpret_cast<unsigned short*>(
                    (char*)Ps + SW(wave * 16 + lc * 4 + r, (kf * 16 + lr) * 2)) = f2b(p[kf][r]);

#pragma unroll
        for (int df = 0; df < 4; df++)
#pragma unroll
            for (int r = 0; r < 4; r++)
                o[df][r] *= alpha[r];

#pragma unroll
        for (int s = 0; s < 2; s++) {
            bf16x8 pa = *reinterpret_cast<const bf16x8*>((char*)Ps + SW(wave * 16 + lr, s * 64 + lc * 16));
#pragma unroll
            for (int df = 0; df < 4; df++) {
                bf16x8 vb = *reinterpret_cast<const bf16x8*>((char*)Vt + SW(df * 16 + lr, s * 64 + lc * 16));
                o[df] = __builtin_amdgcn_mfma_f32_16x16x32_bf16(pa, vb, o[df], 0, 0, 0);
            }
        }
        __syncthreads();   // all Ks/Vt reads done before next staging
    }

    unsigned short* obase = ctx + ((size_t)(b * NSEQ + qt * 64 + wave * 16)) * D + hh * DH;
#pragma unroll
    for (int r = 0; r < 4; r++) {
        float inv = 1.0f / lrow[r];
        int q = lc * 4 + r;
#pragma unroll
        for (int df = 0; df < 4; df++)
            obase[(size_t)q * D + df * 16 + lr] = f2b(o[df][r] * inv);
    }
}

// ---------------------------------------------------------------------------
// 5. Final LN output (fp32) -> attn_res [N,B,D]
__global__ __launch_bounds__(256) void store_attnres(
    const float* __restrict__ hf, float* __restrict__ out)
{
    int idx = blockIdx.x * 256 + threadIdx.x;
    int d  = idx & (D - 1);
    int nb = idx >> 9;      // n*B + b
    int b  = nb & (B - 1);
    int n  = nb >> 4;
    out[idx] = hf[((size_t)(b * NSEQ + n)) * D + d];
}

// ---------------------------------------------------------------------------
// 6. la = hf @ inf_W[:D], lb = hf @ inf_W[D:]. One block per token, shfl reduce.
__global__ __launch_bounds__(256) void lalb_kernel(
    const float* __restrict__ hf, const float* __restrict__ infW,
    float* __restrict__ la, float* __restrict__ lb)
{
    __shared__ float r24[24];
    int t = blockIdx.x, tid = threadIdx.x;
    const float* p = hf + (size_t)t * D;
    float x0 = p[tid], x1 = p[tid + 256];
    float s[6];
#pragma unroll
    for (int c = 0; c < 3; c++) {
        s[c]     = x0 * infW[(size_t)tid * C + c]         + x1 * infW[(size_t)(tid + 256) * C + c];
        s[3 + c] = x0 * infW[(size_t)(tid + 512) * C + c] + x1 * infW[(size_t)(tid + 768) * C + c];
    }
#pragma unroll
    for (int c = 0; c < 6; c++)
#pragma unroll
        for (int o = 32; o > 0; o >>= 1) s[c] += __shfl_xor(s[c], o, 64);
    if ((tid & 63) == 0) {
#pragma unroll
        for (int c = 0; c < 6; c++) r24[c * 4 + (tid >> 6)] = s[c];
    }
    __syncthreads();
    if (tid < 6) {
        float v = r24[tid * 4] + r24[tid * 4 + 1] + r24[tid * 4 + 2] + r24[tid * 4 + 3];
        if (tid < 3) la[(size_t)t * C + tid] = v;
        else         lb[(size_t)t * C + tid - 3] = v;
    }
}

// ---------------------------------------------------------------------------
// 7. logits + log_softmax over C=3; out at [(i*N+j)*B + b]*C + c
__global__ __launch_bounds__(256) void logits_kernel(
    const float* __restrict__ la, const float* __restrict__ lb,
    float* __restrict__ out)
{
    int idx = blockIdx.x * 256 + threadIdx.x;  // over N*N*B
    int b  = idx & (B - 1);
    int ij = idx >> 4;
    int j  = ij & (NSEQ - 1);
    int i  = ij >> 9;
    const float* pa = la + ((size_t)(b * NSEQ + i)) * C;
    const float* pb = lb + ((size_t)(b * NSEQ + j)) * C;
    float l0 = pa[0] + pb[0];
    float l1 = pa[1] + pb[1];
    float l2 = pa[2] + pb[2];
    float m = fmaxf(l0, fmaxf(l1, l2));
    float lse = m + logf(__expf(l0 - m) + __expf(l1 - m) + __expf(l2 - m));
    out[(size_t)idx * 3 + 0] = l0 - lse;
    out[(size_t)idx * 3 + 1] = l1 - lse;
    out[(size_t)idx * 3 + 2] = l2 - lse;
}

// ---------------------------------------------------------------------------
extern "C" void kernel_launch(void* const* d_in, const int* in_sizes, int n_in,
                              void* d_out, int out_size, void* d_ws, size_t ws_size,
                              hipStream_t stream)
{
    const int*   src     = (const int*)  d_in[0];
    const int*   lengths = (const int*)  d_in[1];
    const float* emb     = (const float*)d_in[2];
    const float* ln1_g   = (const float*)d_in[3];
    const float* ln1_b   = (const float*)d_in[4];
    const float* Wq      = (const float*)d_in[5];
    const float* bq      = (const float*)d_in[6];
    const float* Wk      = (const float*)d_in[7];
    const float* bk      = (const float*)d_in[8];
    const float* Wv      = (const float*)d_in[9];
    const float* bv      = (const float*)d_in[10];
    const float* Wo      = (const float*)d_in[11];
    const float* bo      = (const float*)d_in[12];
    const float* ln2_g   = (const float*)d_in[13];
    const float* ln2_b   = (const float*)d_in[14];
    const float* W1      = (const float*)d_in[15];
    const float* b1      = (const float*)d_in[16];
    const float* W2      = (const float*)d_in[17];
    const float* b2      = (const float*)d_in[18];
    const float* lnf_g   = (const float*)d_in[19];
    const float* lnf_b   = (const float*)d_in[20];
    const float* infW    = (const float*)d_in[21];

    // Workspace layout (exactly 5*BND*4 = 83,886,080 bytes):
    //   x      fp32  [M][D]          16,777,216 B
    //   h      bf16  [M][D]           8,388,608 B
    //   wts    bf16  (QKVt,WOt,W1t,W2t) 25,165,824 B
    //   big    union: {q/k/vt bf16 | ffh bf16 | hf fp32 + la/lb}
    char* wsb = (char*)d_ws;
    float*          x   = (float*)wsb;
    unsigned short* h   = (unsigned short*)(wsb + (size_t)BND * 4);
    unsigned short* wts = (unsigned short*)(wsb + (size_t)BND * 4 + (size_t)BND * 2);
    char*           big = wsb + (size_t)BND * 4 + (size_t)BND * 2 + 25165824;

    unsigned short* qbm = (unsigned short*)big;
    unsigned short* kbm = qbm + (size_t)M * D;
    unsigned short* vtm = kbm + (size_t)M * D;   // V^T: [b*512 + dcol][n]
    unsigned short* ffh = (unsigned short*)big;
    float*          hf  = (float*)big;
    float*          la  = hf + BND;
    float*          lb  = la + (size_t)M * C;

    unsigned short* QKVt = wts;                         // [L][3*D][D]
    unsigned short* WOt  = QKVt + (size_t)L * 3 * D * D;
    unsigned short* W1t  = WOt + (size_t)L * D * D;     // [L][DFF][D]
    unsigned short* W2t  = W1t + (size_t)L * D * DFF;   // [L][D][DFF]

    dim3 blk(256);

    // weight convert+transpose (per launch; ~30 us total)
    conv_t_kernel<<<dim3(D / 32, D / 32, L), blk, 0, stream>>>(Wq, QKVt,             D, D, 3 * D * D);
    conv_t_kernel<<<dim3(D / 32, D / 32, L), blk, 0, stream>>>(Wk, QKVt + D * D,     D, D, 3 * D * D);
    conv_t_kernel<<<dim3(D / 32, D / 32, L), blk, 0, stream>>>(Wv, QKVt + 2 * D * D, D, D, 3 * D * D);
    conv_t_kernel<<<dim3(D / 32, D / 32, L), blk, 0, stream>>>(Wo, WOt, D, D, D * D);
    conv_t_kernel<<<dim3(DFF / 32, D / 32, L), blk, 0, stream>>>(W1, W1t, D, DFF, D * DFF);
    conv_t_kernel<<<dim3(D / 32, DFF / 32, L), blk, 0, stream>>>(W2, W2t, DFF, D, DFF * D);

    embed_pe_kernel<<<BND / 256, blk, 0, stream>>>(src, emb, x);

    dim3 gqkv(3 * D / 128, M / 128);        // 12 x 64 = 768 blocks
    dim3 gwo(D / 128, M / 128, 2);          // 4 x 64 x 2 (split-K)
    dim3 gw1(DFF / 128, M / 128);           // 16 x 64
    dim3 gw2(D / 128, M / 128, 4);          // 4 x 64 x 4 (split-K)
    dim3 gattn(NSEQ / 64, H, B);            // 8 x 8 x 16

    for (int l = 0; l < L; l++) {
        size_t bd = (size_t)l * D;
        size_t wqkv = (size_t)l * 3 * D * D, wdd = (size_t)l * D * D;
        size_t wdf = (size_t)l * D * DFF, bf1 = (size_t)l * DFF;
        ln_kernel<1><<<M, blk, 0, stream>>>(x, ln1_g + bd, ln1_b + bd, h);
        mfma_gemm<3, 1><<<gqkv, blk, 0, stream>>>(
            h, QKVt + wqkv, bq + bd, bk + bd, bv + bd, qbm, kbm, vtm, D, 3 * D);
        attn_mfma_kernel<<<gattn, blk, 0, stream>>>(qbm, kbm, vtm, lengths, h);
        mfma_gemm<0, 2><<<gwo, blk, 0, stream>>>(
            h, WOt + wdd, bo + bd, nullptr, nullptr, x, nullptr, nullptr, D, D);
        ln_kernel<1><<<M, blk, 0, stream>>>(x, ln2_g + bd, ln2_b + bd, h);
        mfma_gemm<2, 1><<<gw1, blk, 0, stream>>>(
            h, W1t + wdf, b1 + bf1, nullptr, nullptr, ffh, nullptr, nullptr, D, DFF);
        mfma_gemm<0, 4><<<gw2, blk, 0, stream>>>(
            ffh, W2t + wdf, b2 + bd, nullptr, nullptr, x, nullptr, nullptr, DFF, D);
    }

    ln_kernel<0><<<M, blk, 0, stream>>>(x, lnf_g, lnf_b, hf);
    store_attnres<<<(NSEQ * B * D) / 256, blk, 0, stream>>>(hf, (float*)d_out);
    lalb_kernel<<<M, blk, 0, stream>>>(hf, infW, la, lb);
    logits_kernel<<<(NSEQ * NSEQ * B) / 256, blk, 0, stream>>>(
        la, lb, (float*)d_out + (size_t)NSEQ * B * D);
}

// Round 5
// 1032.881 us; speedup vs baseline: 1.1255x; 1.1255x over previous
//
#include <hip/hip_runtime.h>

// Problem constants
constexpr int L = 4, D = 512, H = 8, DFF = 2048, NSEQ = 512, B = 16, C = 3;
constexpr int DH = D / H;          // 64
constexpr int M = B * NSEQ;        // 8192 tokens
constexpr int BND = B * NSEQ * D;  // 4,194,304

typedef short bf16x8 __attribute__((ext_vector_type(8)));
typedef float f32x4 __attribute__((ext_vector_type(4)));

// bf16 helpers (OCP bf16 = top 16 bits of fp32)
__device__ __forceinline__ float blo(unsigned u) { return __uint_as_float(u << 16); }
__device__ __forceinline__ float bhi(unsigned u) { return __uint_as_float(u & 0xffff0000u); }
__device__ __forceinline__ unsigned short f2b(float f) {   // RNE
    unsigned u = __float_as_uint(f);
    u += 0x7fffu + ((u >> 16) & 1u);
    return (unsigned short)(u >> 16);
}
__device__ __forceinline__ void gload_lds16(const void* g, void* l) {
    __builtin_amdgcn_global_load_lds(
        (const __attribute__((address_space(1))) void*)g,
        (__attribute__((address_space(3))) void*)l, 16, 0, 0);
}

__device__ __forceinline__ float block_sum256(float v, float* r4) {
#pragma unroll
    for (int o = 32; o > 0; o >>= 1) v += __shfl_xor(v, o, 64);
    if ((threadIdx.x & 63) == 0) r4[threadIdx.x >> 6] = v;
    __syncthreads();
    return r4[0] + r4[1] + r4[2] + r4[3];
}

// ---------------------------------------------------------------------------
// 0. Weight convert + transpose: in fp32 [K][N] -> out bf16 [N][K].
//    grid.z = L; per-layer output stride lstride (shorts).
__global__ __launch_bounds__(256) void conv_t_kernel(
    const float* __restrict__ in, unsigned short* __restrict__ out,
    int K, int N, int lstride)
{
    __shared__ float t[32][33];
    int n0 = blockIdx.x * 32, k0 = blockIdx.y * 32;
    const float* ip = in + (size_t)blockIdx.z * K * N;
    unsigned short* op = out + (size_t)blockIdx.z * lstride;
    int tx = threadIdx.x & 31, ty = threadIdx.x >> 5;   // 32 x 8
#pragma unroll
    for (int i = 0; i < 4; i++)
        t[ty + i * 8][tx] = ip[(size_t)(k0 + ty + i * 8) * N + n0 + tx];
    __syncthreads();
#pragma unroll
    for (int i = 0; i < 4; i++)
        op[(size_t)(n0 + ty + i * 8) * K + k0 + tx] = f2b(t[tx][ty + i * 8]);
}

// ---------------------------------------------------------------------------
// 1. Embedding * sqrt(D) + sinusoidal PE.  x[b,n,d] fp32.
__global__ __launch_bounds__(256) void embed_pe_kernel(
    const int* __restrict__ src, const float* __restrict__ emb,
    float* __restrict__ x)
{
    int idx = blockIdx.x * 256 + threadIdx.x;   // over B*N*D
    int d = idx & (D - 1);
    int t = idx >> 9;            // b*N + n
    int n = t & (NSEQ - 1);
    int b = t >> 9;
    int tok = src[n * B + b];
    float e = emb[(size_t)tok * D + d] * 22.627416997969522f;  // sqrt(512)
    float div = expf((float)(d & ~1) * -0.01798894603797866f); // -ln(1e4)/512
    float ang = (float)n * div;
    float pe = (d & 1) ? cosf(ang) : sinf(ang);
    x[idx] = e + pe;
}

// ---------------------------------------------------------------------------
// 2. LayerNorm over D=512, one block (256 thr) per row. Optional bf16 output.
template<int BF16OUT>
__global__ __launch_bounds__(256) void ln_kernel(
    const float* __restrict__ in, const float* __restrict__ g,
    const float* __restrict__ bt, void* __restrict__ outv)
{
    __shared__ float ra[4], rb[4];
    int row = blockIdx.x, tid = threadIdx.x;
    const float* p = in + (size_t)row * D;
    float v0 = p[tid], v1 = p[tid + 256];
    float mean = block_sum256(v0 + v1, ra) * (1.0f / D);
    float d0 = v0 - mean, d1 = v1 - mean;
    float var = block_sum256(d0 * d0 + d1 * d1, rb) * (1.0f / D);
    float rstd = rsqrtf(var + 1e-6f);
    float o0 = d0 * rstd * g[tid] + bt[tid];
    float o1 = d1 * rstd * g[tid + 256] + bt[tid + 256];
    if (BF16OUT) {
        unsigned short* o = (unsigned short*)outv + (size_t)row * D;
        o[tid] = f2b(o0); o[tid + 256] = f2b(o1);
    } else {
        float* o = (float*)outv + (size_t)row * D;
        o[tid] = o0; o[tid + 256] = o1;
    }
}

// ---------------------------------------------------------------------------
// 3. bf16 MFMA GEMM: 128x128 tile, BK=64, 4 waves, double-buffered LDS
//    (T3 2-phase: stage next K-tile before computing current; one barrier/tile).
//    LDS rows are 128 B -> XOR-swizzle 16B slots: global source pre-swizzled
//    (gload_lds writes linearly), reads XOR the same pattern (rule #21/m173).
//    EPI: 0 = fp32 += into out0
//         2 = bf16 relu store
//         3 = fused QKV routing: Q->out0, K->out1, V^T->out2 (all bf16)
template<int EPI>
__global__ __launch_bounds__(256) void mfma_gemm(
    const unsigned short* __restrict__ A,    // [Mrows][Kdim] bf16
    const unsigned short* __restrict__ Wt,   // [Ndim][Kdim] bf16 (pre-transposed)
    const float* __restrict__ biasQ, const float* __restrict__ biasK,
    const float* __restrict__ biasV,
    void* __restrict__ out0, void* __restrict__ out1, void* __restrict__ out2,
    int Kdim, int Ndim)
{
    __shared__ __align__(16) unsigned short As[2][128 * 64];  // 2 x 16 KB
    __shared__ __align__(16) unsigned short Bs[2][128 * 64];  // 2 x 16 KB
    int tid = threadIdx.x;
    int wave = tid >> 6, lane = tid & 63;
    int lr = lane & 15, lc = lane >> 4;      // frag row(m/n), k-group
    int m0 = blockIdx.y * 128, n0 = blockIdx.x * 128;
    int wm = (wave >> 1) * 64, wn = (wave & 1) * 64;

    // staging: thread tid covers row (chunk*32 + (tid>>3)), 16B slot (tid&7).
    // LDS dest is linear (slot tid&7); global source slot is pre-swizzled.
    int srow  = tid >> 3;                    // 0..31 within chunk
    int sslot = (tid & 7) ^ (srow & 7);      // swizzled global 16B slot
    const unsigned short* Ab = A  + ((size_t)(m0 + srow)) * Kdim + sslot * 8;
    const unsigned short* Bb = Wt + ((size_t)(n0 + srow)) * Kdim + sslot * 8;
    int lbase = wave * 512;                  // wave-uniform LDS offset (shorts)

    int nsteps = Kdim >> 6;
    f32x4 acc[4][4] = {};

    auto STAGE = [&](int b, int s) {
        int kb = s << 6;
#pragma unroll
        for (int ch = 0; ch < 4; ch++) {
            gload_lds16(Ab + kb + (size_t)(ch * 32) * Kdim, &As[b][ch * 2048 + lbase]);
            gload_lds16(Bb + kb + (size_t)(ch * 32) * Kdim, &Bs[b][ch * 2048 + lbase]);
        }
    };

    STAGE(0, 0);
    __syncthreads();                 // compiler drains vmcnt(0) before barrier

    for (int s = 0; s < nsteps; s++) {
        int cur = s & 1;
        if (s + 1 < nsteps) STAGE(cur ^ 1, s + 1);   // async, in flight over MFMA
#pragma unroll
        for (int kk = 0; kk < 2; kk++) {
            bf16x8 aF[4], bF[4];
#pragma unroll
            for (int i = 0; i < 4; i++) {
                int ra = wm + i * 16 + lr, rb = wn + i * 16 + lr;
                int sl = ((kk * 4 + lc) ^ (lr & 7)) * 16;   // swizzled 16B slot
                aF[i] = *reinterpret_cast<const bf16x8*>((char*)As[cur] + ra * 128 + sl);
                bF[i] = *reinterpret_cast<const bf16x8*>((char*)Bs[cur] + rb * 128 + sl);
            }
#pragma unroll
            for (int i = 0; i < 4; i++)
#pragma unroll
                for (int j = 0; j < 4; j++)
                    acc[i][j] = __builtin_amdgcn_mfma_f32_16x16x32_bf16(aF[i], bF[j], acc[i][j], 0, 0, 0);
        }
        __syncthreads();             // next tile staged; buf[cur] free for s+2
    }

    // epilogue: C row = (lane>>4)*4 + r, col = lane&15  (m89-verified layout)
#pragma unroll
    for (int i = 0; i < 4; i++) {
        int grow = m0 + wm + i * 16 + lc * 4;
#pragma unroll
        for (int j = 0; j < 4; j++) {
            int gcol = n0 + wn + j * 16 + lr;
            float bv;
            if (EPI == 3)
                bv = (gcol < D) ? biasQ[gcol]
                   : (gcol < 2 * D) ? biasK[gcol - D] : biasV[gcol - 2 * D];
            else
                bv = biasQ[gcol];
#pragma unroll
            for (int r = 0; r < 4; r++) {
                float v = acc[i][j][r] + bv;
                if (EPI == 2) v = fmaxf(v, 0.0f);
                int tok = grow + r;
                if (EPI == 0) {
                    ((float*)out0)[(size_t)tok * Ndim + gcol] += v;
                } else if (EPI == 3) {
                    if (gcol < D)
                        ((unsigned short*)out0)[(size_t)tok * D + gcol] = f2b(v);
                    else if (gcol < 2 * D)
                        ((unsigned short*)out1)[(size_t)tok * D + gcol - D] = f2b(v);
                    else {
                        int dcol = gcol - 2 * D;   // V^T: [(b*512 + dcol)][n]
                        ((unsigned short*)out2)[
                            (((size_t)(tok >> 9) << 9) + dcol) * NSEQ + (tok & (NSEQ - 1))] = f2b(v);
                    }
                } else {
                    ((unsigned short*)out0)[(size_t)tok * Ndim + gcol] = f2b(v);
                }
            }
        }
    }
}

// ---------------------------------------------------------------------------
// 4. Flash attention, MFMA core. bf16 Q/K/V^T in, bf16 ctx out.
//    One block per (b, h, 64-q-tile); 4 waves, each owns a 16-row q-strip.
__global__ __launch_bounds__(256, 3) void attn_mfma_kernel(
    const unsigned short* __restrict__ qg, const unsigned short* __restrict__ kg,
    const unsigned short* __restrict__ vtg, const int* __restrict__ lengths,
    unsigned short* __restrict__ ctx)
{
    __shared__ __align__(16) unsigned short Ks[64 * 64];  // [kv][d] swizzled
    __shared__ __align__(16) unsigned short Vt[64 * 64];  // [d][kv] swizzled
    __shared__ __align__(16) unsigned short Ps[64 * 64];  // Q staging, then P [q][kv]

    int tid = threadIdx.x;
    int wave = tid >> 6, lane = tid & 63;
    int lr = lane & 15, lc = lane >> 4;
    int qt = blockIdx.x, hh = blockIdx.y, b = blockIdx.z;
    int len = lengths[b];

    const unsigned short* qbase  = qg  + ((size_t)(b * NSEQ + qt * 64)) * D + hh * DH;
    const unsigned short* kbase  = kg  + ((size_t)(b * NSEQ)) * D + hh * DH;
    const unsigned short* vtbase = vtg + ((size_t)(b * D + hh * DH)) * NSEQ;

    auto SW = [](int row, int colbyte) { return row * 128 + (colbyte ^ ((row & 7) << 4)); };

#pragma unroll
    for (int it = 0; it < 2; it++) {
        int c = it * 256 + tid;
        int row = c >> 3, d0 = (c & 7) << 3;
        uint4 t = *reinterpret_cast<const uint4*>(qbase + (size_t)row * D + d0);
        *reinterpret_cast<uint4*>((char*)Ps + SW(row, d0 * 2)) = t;
    }
    __syncthreads();
    bf16x8 aQ[2];
#pragma unroll
    for (int s = 0; s < 2; s++)
        aQ[s] = *reinterpret_cast<const bf16x8*>((char*)Ps + SW(wave * 16 + lr, s * 64 + lc * 16));

    f32x4 o[4] = {};
    float mrow[4], lrow[4];
#pragma unroll
    for (int r = 0; r < 4; r++) { mrow[r] = -INFINITY; lrow[r] = 0.0f; }

    for (int kt = 0; kt < 8; kt++) {
#pragma unroll
        for (int it = 0; it < 2; it++) {
            int c = it * 256 + tid;
            int row = c >> 3, d0 = (c & 7) << 3;
            uint4 t = *reinterpret_cast<const uint4*>(kbase + (size_t)(kt * 64 + row) * D + d0);
            *reinterpret_cast<uint4*>((char*)Ks + SW(row, d0 * 2)) = t;
            uint4 tv = *reinterpret_cast<const uint4*>(vtbase + (size_t)row * NSEQ + kt * 64 + d0);
            *reinterpret_cast<uint4*>((char*)Vt + SW(row, d0 * 2)) = tv;
        }
        __syncthreads();

        f32x4 sacc[4] = {};
#pragma unroll
        for (int kf = 0; kf < 4; kf++) {
#pragma unroll
            for (int s = 0; s < 2; s++) {
                bf16x8 bK = *reinterpret_cast<const bf16x8*>((char*)Ks + SW(kf * 16 + lr, s * 64 + lc * 16));
                sacc[kf] = __builtin_amdgcn_mfma_f32_16x16x32_bf16(aQ[s], bK, sacc[kf], 0, 0, 0);
            }
        }

        float p[4][4], tm[4];
#pragma unroll
        for (int r = 0; r < 4; r++) tm[r] = -INFINITY;
#pragma unroll
        for (int kf = 0; kf < 4; kf++) {
            int col = kt * 64 + kf * 16 + lr;
            bool ok = col < len;
#pragma unroll
            for (int r = 0; r < 4; r++) {
                float sv = ok ? sacc[kf][r] * 0.125f : -1e9f;
                p[kf][r] = sv;
                tm[r] = fmaxf(tm[r], sv);
            }
        }
#pragma unroll
        for (int r = 0; r < 4; r++) {
#pragma unroll
            for (int msk = 1; msk < 16; msk <<= 1)
                tm[r] = fmaxf(tm[r], __shfl_xor(tm[r], msk, 64));
        }
        float alpha[4], ps[4];
#pragma unroll
        for (int r = 0; r < 4; r++) {
            float nm = fmaxf(mrow[r], tm[r]);
            alpha[r] = __expf(mrow[r] - nm);
            mrow[r] = nm;
            ps[r] = 0.0f;
        }
#pragma unroll
        for (int kf = 0; kf < 4; kf++)
#pragma unroll
            for (int r = 0; r < 4; r++) {
                float e = __expf(p[kf][r] - mrow[r]);
                p[kf][r] = e;
                ps[r] += e;
            }
#pragma unroll
        for (int r = 0; r < 4; r++) {
#pragma unroll
            for (int msk = 1; msk < 16; msk <<= 1)
                ps[r] += __shfl_xor(ps[r], msk, 64);
            lrow[r] = lrow[r] * alpha[r] + ps[r];
        }

#pragma unroll
        for (int kf = 0; kf < 4; kf++)
#pragma unroll
            for (int r = 0; r < 4; r++)
                *reinterpret_cast<unsigned short*>(
                    (char*)Ps + SW(wave * 16 + lc * 4 + r, (kf * 16 + lr) * 2)) = f2b(p[kf][r]);

#pragma unroll
        for (int df = 0; df < 4; df++)
#pragma unroll
            for (int r = 0; r < 4; r++)
                o[df][r] *= alpha[r];

#pragma unroll
        for (int s = 0; s < 2; s++) {
            bf16x8 pa = *reinterpret_cast<const bf16x8*>((char*)Ps + SW(wave * 16 + lr, s * 64 + lc * 16));
#pragma unroll
            for (int df = 0; df < 4; df++) {
                bf16x8 vb = *reinterpret_cast<const bf16x8*>((char*)Vt + SW(df * 16 + lr, s * 64 + lc * 16));
                o[df] = __builtin_amdgcn_mfma_f32_16x16x32_bf16(pa, vb, o[df], 0, 0, 0);
            }
        }
        __syncthreads();   // all Ks/Vt reads done before next staging
    }

    unsigned short* obase = ctx + ((size_t)(b * NSEQ + qt * 64 + wave * 16)) * D + hh * DH;
#pragma unroll
    for (int r = 0; r < 4; r++) {
        float inv = 1.0f / lrow[r];
        int q = lc * 4 + r;
#pragma unroll
        for (int df = 0; df < 4; df++)
            obase[(size_t)q * D + df * 16 + lr] = f2b(o[df][r] * inv);
    }
}

// ---------------------------------------------------------------------------
// 5. Final LN output (fp32) -> attn_res [N,B,D]
__global__ __launch_bounds__(256) void store_attnres(
    const float* __restrict__ hf, float* __restrict__ out)
{
    int idx = blockIdx.x * 256 + threadIdx.x;
    int d  = idx & (D - 1);
    int nb = idx >> 9;      // n*B + b
    int b  = nb & (B - 1);
    int n  = nb >> 4;
    out[idx] = hf[((size_t)(b * NSEQ + n)) * D + d];
}

// ---------------------------------------------------------------------------
// 6. la = hf @ inf_W[:D], lb = hf @ inf_W[D:]. One block per token, shfl reduce.
__global__ __launch_bounds__(256) void lalb_kernel(
    const float* __restrict__ hf, const float* __restrict__ infW,
    float* __restrict__ la, float* __restrict__ lb)
{
    __shared__ float r24[24];
    int t = blockIdx.x, tid = threadIdx.x;
    const float* p = hf + (size_t)t * D;
    float x0 = p[tid], x1 = p[tid + 256];
    float s[6];
#pragma unroll
    for (int c = 0; c < 3; c++) {
        s[c]     = x0 * infW[(size_t)tid * C + c]         + x1 * infW[(size_t)(tid + 256) * C + c];
        s[3 + c] = x0 * infW[(size_t)(tid + 512) * C + c] + x1 * infW[(size_t)(tid + 768) * C + c];
    }
#pragma unroll
    for (int c = 0; c < 6; c++)
#pragma unroll
        for (int o = 32; o > 0; o >>= 1) s[c] += __shfl_xor(s[c], o, 64);
    if ((tid & 63) == 0) {
#pragma unroll
        for (int c = 0; c < 6; c++) r24[c * 4 + (tid >> 6)] = s[c];
    }
    __syncthreads();
    if (tid < 6) {
        float v = r24[tid * 4] + r24[tid * 4 + 1] + r24[tid * 4 + 2] + r24[tid * 4 + 3];
        if (tid < 3) la[(size_t)t * C + tid] = v;
        else         lb[(size_t)t * C + tid - 3] = v;
    }
}

// ---------------------------------------------------------------------------
// 7. logits + log_softmax over C=3; out at [(i*N+j)*B + b]*C + c
__global__ __launch_bounds__(256) void logits_kernel(
    const float* __restrict__ la, const float* __restrict__ lb,
    float* __restrict__ out)
{
    int idx = blockIdx.x * 256 + threadIdx.x;  // over N*N*B
    int b  = idx & (B - 1);
    int ij = idx >> 4;
    int j  = ij & (NSEQ - 1);
    int i  = ij >> 9;
    const float* pa = la + ((size_t)(b * NSEQ + i)) * C;
    const float* pb = lb + ((size_t)(b * NSEQ + j)) * C;
    float l0 = pa[0] + pb[0];
    float l1 = pa[1] + pb[1];
    float l2 = pa[2] + pb[2];
    float m = fmaxf(l0, fmaxf(l1, l2));
    float lse = m + logf(__expf(l0 - m) + __expf(l1 - m) + __expf(l2 - m));
    out[(size_t)idx * 3 + 0] = l0 - lse;
    out[(size_t)idx * 3 + 1] = l1 - lse;
    out[(size_t)idx * 3 + 2] = l2 - lse;
}

// ---------------------------------------------------------------------------
extern "C" void kernel_launch(void* const* d_in, const int* in_sizes, int n_in,
                              void* d_out, int out_size, void* d_ws, size_t ws_size,
                              hipStream_t stream)
{
    const int*   src     = (const int*)  d_in[0];
    const int*   lengths = (const int*)  d_in[1];
    const float* emb     = (const float*)d_in[2];
    const float* ln1_g   = (const float*)d_in[3];
    const float* ln1_b   = (const float*)d_in[4];
    const float* Wq      = (const float*)d_in[5];
    const float* bq      = (const float*)d_in[6];
    const float* Wk      = (const float*)d_in[7];
    const float* bk      = (const float*)d_in[8];
    const float* Wv      = (const float*)d_in[9];
    const float* bv      = (const float*)d_in[10];
    const float* Wo      = (const float*)d_in[11];
    const float* bo      = (const float*)d_in[12];
    const float* ln2_g   = (const float*)d_in[13];
    const float* ln2_b   = (const float*)d_in[14];
    const float* W1      = (const float*)d_in[15];
    const float* b1      = (const float*)d_in[16];
    const float* W2      = (const float*)d_in[17];
    const float* b2      = (const float*)d_in[18];
    const float* lnf_g   = (const float*)d_in[19];
    const float* lnf_b   = (const float*)d_in[20];
    const float* infW    = (const float*)d_in[21];

    // Workspace layout (exactly 5*BND*4 = 83,886,080 bytes):
    //   x      fp32  [M][D]          16,777,216 B
    //   h      bf16  [M][D]           8,388,608 B
    //   wts    bf16  (QKVt,WOt,W1t,W2t) 25,165,824 B
    //   big    union: {q/k/vt bf16 | ffh bf16 | hf fp32 + la/lb}
    char* wsb = (char*)d_ws;
    float*          x   = (float*)wsb;
    unsigned short* h   = (unsigned short*)(wsb + (size_t)BND * 4);
    unsigned short* wts = (unsigned short*)(wsb + (size_t)BND * 4 + (size_t)BND * 2);
    char*           big = wsb + (size_t)BND * 4 + (size_t)BND * 2 + 25165824;

    unsigned short* qbm = (unsigned short*)big;
    unsigned short* kbm = qbm + (size_t)M * D;
    unsigned short* vtm = kbm + (size_t)M * D;   // V^T: [b*512 + dcol][n]
    unsigned short* ffh = (unsigned short*)big;
    float*          hf  = (float*)big;
    float*          la  = hf + BND;
    float*          lb  = la + (size_t)M * C;

    unsigned short* QKVt = wts;                         // [L][3*D][D]
    unsigned short* WOt  = QKVt + (size_t)L * 3 * D * D;
    unsigned short* W1t  = WOt + (size_t)L * D * D;     // [L][DFF][D]
    unsigned short* W2t  = W1t + (size_t)L * D * DFF;   // [L][D][DFF]

    dim3 blk(256);

    // weight convert+transpose (per launch; ~30 us total)
    conv_t_kernel<<<dim3(D / 32, D / 32, L), blk, 0, stream>>>(Wq, QKVt,             D, D, 3 * D * D);
    conv_t_kernel<<<dim3(D / 32, D / 32, L), blk, 0, stream>>>(Wk, QKVt + D * D,     D, D, 3 * D * D);
    conv_t_kernel<<<dim3(D / 32, D / 32, L), blk, 0, stream>>>(Wv, QKVt + 2 * D * D, D, D, 3 * D * D);
    conv_t_kernel<<<dim3(D / 32, D / 32, L), blk, 0, stream>>>(Wo, WOt, D, D, D * D);
    conv_t_kernel<<<dim3(DFF / 32, D / 32, L), blk, 0, stream>>>(W1, W1t, D, DFF, D * DFF);
    conv_t_kernel<<<dim3(D / 32, DFF / 32, L), blk, 0, stream>>>(W2, W2t, DFF, D, DFF * D);

    embed_pe_kernel<<<BND / 256, blk, 0, stream>>>(src, emb, x);

    dim3 gqkv(3 * D / 128, M / 128);        // 12 x 64 = 768 blocks
    dim3 gwo(D / 128, M / 128);             // 4 x 64 = 256 blocks
    dim3 gw1(DFF / 128, M / 128);           // 16 x 64 = 1024 blocks
    dim3 gw2(D / 128, M / 128);             // 4 x 64 = 256 blocks
    dim3 gattn(NSEQ / 64, H, B);            // 8 x 8 x 16

    for (int l = 0; l < L; l++) {
        size_t bd = (size_t)l * D;
        size_t wqkv = (size_t)l * 3 * D * D, wdd = (size_t)l * D * D;
        size_t wdf = (size_t)l * D * DFF, bf1 = (size_t)l * DFF;
        ln_kernel<1><<<M, blk, 0, stream>>>(x, ln1_g + bd, ln1_b + bd, h);
        mfma_gemm<3><<<gqkv, blk, 0, stream>>>(
            h, QKVt + wqkv, bq + bd, bk + bd, bv + bd, qbm, kbm, vtm, D, 3 * D);
        attn_mfma_kernel<<<gattn, blk, 0, stream>>>(qbm, kbm, vtm, lengths, h);
        mfma_gemm<0><<<gwo, blk, 0, stream>>>(
            h, WOt + wdd, bo + bd, nullptr, nullptr, x, nullptr, nullptr, D, D);
        ln_kernel<1><<<M, blk, 0, stream>>>(x, ln2_g + bd, ln2_b + bd, h);
        mfma_gemm<2><<<gw1, blk, 0, stream>>>(
            h, W1t + wdf, b1 + bf1, nullptr, nullptr, ffh, nullptr, nullptr, D, DFF);
        mfma_gemm<0><<<gw2, blk, 0, stream>>>(
            ffh, W2t + wdf, b2 + bd, nullptr, nullptr, x, nullptr, nullptr, DFF, D);
    }

    ln_kernel<0><<<M, blk, 0, stream>>>(x, lnf_g, lnf_b, hf);
    store_attnres<<<(NSEQ * B * D) / 256, blk, 0, stream>>>(hf, (float*)d_out);
    lalb_kernel<<<M, blk, 0, stream>>>(hf, infW, la, lb);
    logits_kernel<<<(NSEQ * NSEQ * B) / 256, blk, 0, stream>>>(
        la, lb, (float*)d_out + (size_t)NSEQ * B * D);
}

// Round 6
// 947.226 us; speedup vs baseline: 1.2273x; 1.0904x over previous
//
#include <hip/hip_runtime.h>

// Problem constants
constexpr int L = 4, D = 512, H = 8, DFF = 2048, NSEQ = 512, B = 16, C = 3;
constexpr int DH = D / H;          // 64
constexpr int M = B * NSEQ;        // 8192 tokens
constexpr int BND = B * NSEQ * D;  // 4,194,304

typedef short bf16x8 __attribute__((ext_vector_type(8)));
typedef float f32x4 __attribute__((ext_vector_type(4)));

// bf16 helpers (OCP bf16 = top 16 bits of fp32)
__device__ __forceinline__ float blo(unsigned u) { return __uint_as_float(u << 16); }
__device__ __forceinline__ float bhi(unsigned u) { return __uint_as_float(u & 0xffff0000u); }
__device__ __forceinline__ unsigned short f2b(float f) {   // RNE
    unsigned u = __float_as_uint(f);
    u += 0x7fffu + ((u >> 16) & 1u);
    return (unsigned short)(u >> 16);
}
__device__ __forceinline__ void gload_lds16(const void* g, void* l) {
    __builtin_amdgcn_global_load_lds(
        (const __attribute__((address_space(1))) void*)g,
        (__attribute__((address_space(3))) void*)l, 16, 0, 0);
}

__device__ __forceinline__ float block_sum256(float v, float* r4) {
#pragma unroll
    for (int o = 32; o > 0; o >>= 1) v += __shfl_xor(v, o, 64);
    if ((threadIdx.x & 63) == 0) r4[threadIdx.x >> 6] = v;
    __syncthreads();
    return r4[0] + r4[1] + r4[2] + r4[3];
}

// ---------------------------------------------------------------------------
// 0. Weight convert + transpose: in fp32 [K][N] -> out bf16 [N][K].
//    grid.z = L; per-layer output stride lstride (shorts).
__global__ __launch_bounds__(256) void conv_t_kernel(
    const float* __restrict__ in, unsigned short* __restrict__ out,
    int K, int N, int lstride)
{
    __shared__ float t[32][33];
    int n0 = blockIdx.x * 32, k0 = blockIdx.y * 32;
    const float* ip = in + (size_t)blockIdx.z * K * N;
    unsigned short* op = out + (size_t)blockIdx.z * lstride;
    int tx = threadIdx.x & 31, ty = threadIdx.x >> 5;   // 32 x 8
#pragma unroll
    for (int i = 0; i < 4; i++)
        t[ty + i * 8][tx] = ip[(size_t)(k0 + ty + i * 8) * N + n0 + tx];
    __syncthreads();
#pragma unroll
    for (int i = 0; i < 4; i++)
        op[(size_t)(n0 + ty + i * 8) * K + k0 + tx] = f2b(t[tx][ty + i * 8]);
}

// ---------------------------------------------------------------------------
// 1. Embedding * sqrt(D) + sinusoidal PE.  x[b,n,d] fp32.
__global__ __launch_bounds__(256) void embed_pe_kernel(
    const int* __restrict__ src, const float* __restrict__ emb,
    float* __restrict__ x)
{
    int idx = blockIdx.x * 256 + threadIdx.x;   // over B*N*D
    int d = idx & (D - 1);
    int t = idx >> 9;            // b*N + n
    int n = t & (NSEQ - 1);
    int b = t >> 9;
    int tok = src[n * B + b];
    float e = emb[(size_t)tok * D + d] * 22.627416997969522f;  // sqrt(512)
    float div = expf((float)(d & ~1) * -0.01798894603797866f); // -ln(1e4)/512
    float ang = (float)n * div;
    float pe = (d & 1) ? cosf(ang) : sinf(ang);
    x[idx] = e + pe;
}

// ---------------------------------------------------------------------------
// 2. LayerNorm over D=512, one block (256 thr) per row. Optional bf16 output.
template<int BF16OUT>
__global__ __launch_bounds__(256) void ln_kernel(
    const float* __restrict__ in, const float* __restrict__ g,
    const float* __restrict__ bt, void* __restrict__ outv)
{
    __shared__ float ra[4], rb[4];
    int row = blockIdx.x, tid = threadIdx.x;
    const float* p = in + (size_t)row * D;
    float v0 = p[tid], v1 = p[tid + 256];
    float mean = block_sum256(v0 + v1, ra) * (1.0f / D);
    float d0 = v0 - mean, d1 = v1 - mean;
    float var = block_sum256(d0 * d0 + d1 * d1, rb) * (1.0f / D);
    float rstd = rsqrtf(var + 1e-6f);
    float o0 = d0 * rstd * g[tid] + bt[tid];
    float o1 = d1 * rstd * g[tid + 256] + bt[tid + 256];
    if (BF16OUT) {
        unsigned short* o = (unsigned short*)outv + (size_t)row * D;
        o[tid] = f2b(o0); o[tid + 256] = f2b(o1);
    } else {
        float* o = (float*)outv + (size_t)row * D;
        o[tid] = o0; o[tid + 256] = o1;
    }
}

// ---------------------------------------------------------------------------
// 3. bf16 MFMA GEMM: 64x128 tile (BM=64, BN=128), BK=64, 4 waves,
//    double-buffered LDS, one barrier per K-tile (T3 2-phase).
//    Each wave owns 64 rows x 32 cols = 4x2 frags of 16x16x32.
//    LDS rows are 128 B; XOR-swizzled 16B slots: source pre-swizzled
//    (gload_lds writes linearly), reads XOR the same pattern (rule #21).
//    EPI: 0 = fp32 += into out0
//         2 = bf16 relu store
//         3 = fused QKV routing: Q->out0, K->out1, V^T->out2 (all bf16)
template<int EPI>
__global__ __launch_bounds__(256) void mfma_gemm(
    const unsigned short* __restrict__ A,    // [Mrows][Kdim] bf16
    const unsigned short* __restrict__ Wt,   // [Ndim][Kdim] bf16 (pre-transposed)
    const float* __restrict__ biasQ, const float* __restrict__ biasK,
    const float* __restrict__ biasV,
    void* __restrict__ out0, void* __restrict__ out1, void* __restrict__ out2,
    int Kdim, int Ndim)
{
    __shared__ __align__(16) unsigned short As[2][64 * 64];    // 2 x 8 KB
    __shared__ __align__(16) unsigned short Bs[2][128 * 64];   // 2 x 16 KB
    int tid = threadIdx.x;
    int wave = tid >> 6, lane = tid & 63;
    int lr = lane & 15, lc = lane >> 4;      // frag row(m/n), k-group
    int m0 = blockIdx.y * 64, n0 = blockIdx.x * 128;
    int wn = wave * 32;                      // wave's 32-col strip

    // staging: thread tid covers row (chunk*32 + (tid>>3)), 16B slot (tid&7).
    // LDS dest is linear (slot tid&7); global source slot is pre-swizzled.
    int srow  = tid >> 3;                    // 0..31 within chunk
    int sslot = (tid & 7) ^ (srow & 7);      // swizzled global 16B slot
    const unsigned short* Ab = A  + ((size_t)(m0 + srow)) * Kdim + sslot * 8;
    const unsigned short* Bb = Wt + ((size_t)(n0 + srow)) * Kdim + sslot * 8;
    int lbase = wave * 512;                  // wave-uniform LDS offset (shorts)

    int nsteps = Kdim >> 6;
    f32x4 acc[4][2] = {};

    auto STAGE = [&](int b, int s) {
        int kb = s << 6;
#pragma unroll
        for (int ch = 0; ch < 2; ch++)
            gload_lds16(Ab + kb + (size_t)(ch * 32) * Kdim, &As[b][ch * 2048 + lbase]);
#pragma unroll
        for (int ch = 0; ch < 4; ch++)
            gload_lds16(Bb + kb + (size_t)(ch * 32) * Kdim, &Bs[b][ch * 2048 + lbase]);
    };

    STAGE(0, 0);
    __syncthreads();                 // compiler drains vmcnt(0) before barrier

    for (int s = 0; s < nsteps; s++) {
        int cur = s & 1;
        if (s + 1 < nsteps) STAGE(cur ^ 1, s + 1);   // async, in flight over MFMA
#pragma unroll
        for (int kk = 0; kk < 2; kk++) {
            int sl = ((kk * 4 + lc) ^ (lr & 7)) * 16;   // swizzled 16B slot
            bf16x8 aF[4], bF[2];
#pragma unroll
            for (int i = 0; i < 4; i++)
                aF[i] = *reinterpret_cast<const bf16x8*>((char*)As[cur] + (i * 16 + lr) * 128 + sl);
#pragma unroll
            for (int j = 0; j < 2; j++)
                bF[j] = *reinterpret_cast<const bf16x8*>((char*)Bs[cur] + (wn + j * 16 + lr) * 128 + sl);
#pragma unroll
            for (int i = 0; i < 4; i++)
#pragma unroll
                for (int j = 0; j < 2; j++)
                    acc[i][j] = __builtin_amdgcn_mfma_f32_16x16x32_bf16(aF[i], bF[j], acc[i][j], 0, 0, 0);
        }
        __syncthreads();             // next tile staged; buf[cur] free for s+2
    }

    // epilogue: C row = (lane>>4)*4 + r, col = lane&15  (m89-verified layout)
#pragma unroll
    for (int i = 0; i < 4; i++) {
        int grow = m0 + i * 16 + lc * 4;
#pragma unroll
        for (int j = 0; j < 2; j++) {
            int gcol = n0 + wn + j * 16 + lr;
            float bv;
            if (EPI == 3)
                bv = (gcol < D) ? biasQ[gcol]
                   : (gcol < 2 * D) ? biasK[gcol - D] : biasV[gcol - 2 * D];
            else
                bv = biasQ[gcol];
#pragma unroll
            for (int r = 0; r < 4; r++) {
                float v = acc[i][j][r] + bv;
                if (EPI == 2) v = fmaxf(v, 0.0f);
                int tok = grow + r;
                if (EPI == 0) {
                    ((float*)out0)[(size_t)tok * Ndim + gcol] += v;
                } else if (EPI == 3) {
                    if (gcol < D)
                        ((unsigned short*)out0)[(size_t)tok * D + gcol] = f2b(v);
                    else if (gcol < 2 * D)
                        ((unsigned short*)out1)[(size_t)tok * D + gcol - D] = f2b(v);
                    else {
                        int dcol = gcol - 2 * D;   // V^T: [(b*512 + dcol)][n]
                        ((unsigned short*)out2)[
                            (((size_t)(tok >> 9) << 9) + dcol) * NSEQ + (tok & (NSEQ - 1))] = f2b(v);
                    }
                } else {
                    ((unsigned short*)out0)[(size_t)tok * Ndim + gcol] = f2b(v);
                }
            }
        }
    }
}

// ---------------------------------------------------------------------------
// 4. Flash attention, MFMA core. bf16 Q/K/V^T in, bf16 ctx out.
//    One block per (b, h, 64-q-tile); 4 waves, each owns a 16-row q-strip.
__global__ __launch_bounds__(256, 3) void attn_mfma_kernel(
    const unsigned short* __restrict__ qg, const unsigned short* __restrict__ kg,
    const unsigned short* __restrict__ vtg, const int* __restrict__ lengths,
    unsigned short* __restrict__ ctx)
{
    __shared__ __align__(16) unsigned short Ks[64 * 64];  // [kv][d] swizzled
    __shared__ __align__(16) unsigned short Vt[64 * 64];  // [d][kv] swizzled
    __shared__ __align__(16) unsigned short Ps[64 * 64];  // Q staging, then P [q][kv]

    int tid = threadIdx.x;
    int wave = tid >> 6, lane = tid & 63;
    int lr = lane & 15, lc = lane >> 4;
    int qt = blockIdx.x, hh = blockIdx.y, b = blockIdx.z;
    int len = lengths[b];

    const unsigned short* qbase  = qg  + ((size_t)(b * NSEQ + qt * 64)) * D + hh * DH;
    const unsigned short* kbase  = kg  + ((size_t)(b * NSEQ)) * D + hh * DH;
    const unsigned short* vtbase = vtg + ((size_t)(b * D + hh * DH)) * NSEQ;

    auto SW = [](int row, int colbyte) { return row * 128 + (colbyte ^ ((row & 7) << 4)); };

#pragma unroll
    for (int it = 0; it < 2; it++) {
        int c = it * 256 + tid;
        int row = c >> 3, d0 = (c & 7) << 3;
        uint4 t = *reinterpret_cast<const uint4*>(qbase + (size_t)row * D + d0);
        *reinterpret_cast<uint4*>((char*)Ps + SW(row, d0 * 2)) = t;
    }
    __syncthreads();
    bf16x8 aQ[2];
#pragma unroll
    for (int s = 0; s < 2; s++)
        aQ[s] = *reinterpret_cast<const bf16x8*>((char*)Ps + SW(wave * 16 + lr, s * 64 + lc * 16));

    f32x4 o[4] = {};
    float mrow[4], lrow[4];
#pragma unroll
    for (int r = 0; r < 4; r++) { mrow[r] = -INFINITY; lrow[r] = 0.0f; }

    for (int kt = 0; kt < 8; kt++) {
#pragma unroll
        for (int it = 0; it < 2; it++) {
            int c = it * 256 + tid;
            int row = c >> 3, d0 = (c & 7) << 3;
            uint4 t = *reinterpret_cast<const uint4*>(kbase + (size_t)(kt * 64 + row) * D + d0);
            *reinterpret_cast<uint4*>((char*)Ks + SW(row, d0 * 2)) = t;
            uint4 tv = *reinterpret_cast<const uint4*>(vtbase + (size_t)row * NSEQ + kt * 64 + d0);
            *reinterpret_cast<uint4*>((char*)Vt + SW(row, d0 * 2)) = tv;
        }
        __syncthreads();

        f32x4 sacc[4] = {};
#pragma unroll
        for (int kf = 0; kf < 4; kf++) {
#pragma unroll
            for (int s = 0; s < 2; s++) {
                bf16x8 bK = *reinterpret_cast<const bf16x8*>((char*)Ks + SW(kf * 16 + lr, s * 64 + lc * 16));
                sacc[kf] = __builtin_amdgcn_mfma_f32_16x16x32_bf16(aQ[s], bK, sacc[kf], 0, 0, 0);
            }
        }

        float p[4][4], tm[4];
#pragma unroll
        for (int r = 0; r < 4; r++) tm[r] = -INFINITY;
#pragma unroll
        for (int kf = 0; kf < 4; kf++) {
            int col = kt * 64 + kf * 16 + lr;
            bool ok = col < len;
#pragma unroll
            for (int r = 0; r < 4; r++) {
                float sv = ok ? sacc[kf][r] * 0.125f : -1e9f;
                p[kf][r] = sv;
                tm[r] = fmaxf(tm[r], sv);
            }
        }
#pragma unroll
        for (int r = 0; r < 4; r++) {
#pragma unroll
            for (int msk = 1; msk < 16; msk <<= 1)
                tm[r] = fmaxf(tm[r], __shfl_xor(tm[r], msk, 64));
        }
        float alpha[4], ps[4];
#pragma unroll
        for (int r = 0; r < 4; r++) {
            float nm = fmaxf(mrow[r], tm[r]);
            alpha[r] = __expf(mrow[r] - nm);
            mrow[r] = nm;
            ps[r] = 0.0f;
        }
#pragma unroll
        for (int kf = 0; kf < 4; kf++)
#pragma unroll
            for (int r = 0; r < 4; r++) {
                float e = __expf(p[kf][r] - mrow[r]);
                p[kf][r] = e;
                ps[r] += e;
            }
#pragma unroll
        for (int r = 0; r < 4; r++) {
#pragma unroll
            for (int msk = 1; msk < 16; msk <<= 1)
                ps[r] += __shfl_xor(ps[r], msk, 64);
            lrow[r] = lrow[r] * alpha[r] + ps[r];
        }

#pragma unroll
        for (int kf = 0; kf < 4; kf++)
#pragma unroll
            for (int r = 0; r < 4; r++)
                *reinterpret_cast<unsigned short*>(
                    (char*)Ps + SW(wave * 16 + lc * 4 + r, (kf * 16 + lr) * 2)) = f2b(p[kf][r]);

#pragma unroll
        for (int df = 0; df < 4; df++)
#pragma unroll
            for (int r = 0; r < 4; r++)
                o[df][r] *= alpha[r];

#pragma unroll
        for (int s = 0; s < 2; s++) {
            bf16x8 pa = *reinterpret_cast<const bf16x8*>((char*)Ps + SW(wave * 16 + lr, s * 64 + lc * 16));
#pragma unroll
            for (int df = 0; df < 4; df++) {
                bf16x8 vb = *reinterpret_cast<const bf16x8*>((char*)Vt + SW(df * 16 + lr, s * 64 + lc * 16));
                o[df] = __builtin_amdgcn_mfma_f32_16x16x32_bf16(pa, vb, o[df], 0, 0, 0);
            }
        }
        __syncthreads();   // all Ks/Vt reads done before next staging
    }

    unsigned short* obase = ctx + ((size_t)(b * NSEQ + qt * 64 + wave * 16)) * D + hh * DH;
#pragma unroll
    for (int r = 0; r < 4; r++) {
        float inv = 1.0f / lrow[r];
        int q = lc * 4 + r;
#pragma unroll
        for (int df = 0; df < 4; df++)
            obase[(size_t)q * D + df * 16 + lr] = f2b(o[df][r] * inv);
    }
}

// ---------------------------------------------------------------------------
// 5. Final LN output (fp32) -> attn_res [N,B,D]
__global__ __launch_bounds__(256) void store_attnres(
    const float* __restrict__ hf, float* __restrict__ out)
{
    int idx = blockIdx.x * 256 + threadIdx.x;
    int d  = idx & (D - 1);
    int nb = idx >> 9;      // n*B + b
    int b  = nb & (B - 1);
    int n  = nb >> 4;
    out[idx] = hf[((size_t)(b * NSEQ + n)) * D + d];
}

// ---------------------------------------------------------------------------
// 6. la = hf @ inf_W[:D], lb = hf @ inf_W[D:]. One block per token, shfl reduce.
__global__ __launch_bounds__(256) void lalb_kernel(
    const float* __restrict__ hf, const float* __restrict__ infW,
    float* __restrict__ la, float* __restrict__ lb)
{
    __shared__ float r24[24];
    int t = blockIdx.x, tid = threadIdx.x;
    const float* p = hf + (size_t)t * D;
    float x0 = p[tid], x1 = p[tid + 256];
    float s[6];
#pragma unroll
    for (int c = 0; c < 3; c++) {
        s[c]     = x0 * infW[(size_t)tid * C + c]         + x1 * infW[(size_t)(tid + 256) * C + c];
        s[3 + c] = x0 * infW[(size_t)(tid + 512) * C + c] + x1 * infW[(size_t)(tid + 768) * C + c];
    }
#pragma unroll
    for (int c = 0; c < 6; c++)
#pragma unroll
        for (int o = 32; o > 0; o >>= 1) s[c] += __shfl_xor(s[c], o, 64);
    if ((tid & 63) == 0) {
#pragma unroll
        for (int c = 0; c < 6; c++) r24[c * 4 + (tid >> 6)] = s[c];
    }
    __syncthreads();
    if (tid < 6) {
        float v = r24[tid * 4] + r24[tid * 4 + 1] + r24[tid * 4 + 2] + r24[tid * 4 + 3];
        if (tid < 3) la[(size_t)t * C + tid] = v;
        else         lb[(size_t)t * C + tid - 3] = v;
    }
}

// ---------------------------------------------------------------------------
// 7. logits + log_softmax over C=3; out at [(i*N+j)*B + b]*C + c
__global__ __launch_bounds__(256) void logits_kernel(
    const float* __restrict__ la, const float* __restrict__ lb,
    float* __restrict__ out)
{
    int idx = blockIdx.x * 256 + threadIdx.x;  // over N*N*B
    int b  = idx & (B - 1);
    int ij = idx >> 4;
    int j  = ij & (NSEQ - 1);
    int i  = ij >> 9;
    const float* pa = la + ((size_t)(b * NSEQ + i)) * C;
    const float* pb = lb + ((size_t)(b * NSEQ + j)) * C;
    float l0 = pa[0] + pb[0];
    float l1 = pa[1] + pb[1];
    float l2 = pa[2] + pb[2];
    float m = fmaxf(l0, fmaxf(l1, l2));
    float lse = m + logf(__expf(l0 - m) + __expf(l1 - m) + __expf(l2 - m));
    out[(size_t)idx * 3 + 0] = l0 - lse;
    out[(size_t)idx * 3 + 1] = l1 - lse;
    out[(size_t)idx * 3 + 2] = l2 - lse;
}

// ---------------------------------------------------------------------------
extern "C" void kernel_launch(void* const* d_in, const int* in_sizes, int n_in,
                              void* d_out, int out_size, void* d_ws, size_t ws_size,
                              hipStream_t stream)
{
    const int*   src     = (const int*)  d_in[0];
    const int*   lengths = (const int*)  d_in[1];
    const float* emb     = (const float*)d_in[2];
    const float* ln1_g   = (const float*)d_in[3];
    const float* ln1_b   = (const float*)d_in[4];
    const float* Wq      = (const float*)d_in[5];
    const float* bq      = (const float*)d_in[6];
    const float* Wk      = (const float*)d_in[7];
    const float* bk      = (const float*)d_in[8];
    const float* Wv      = (const float*)d_in[9];
    const float* bv      = (const float*)d_in[10];
    const float* Wo      = (const float*)d_in[11];
    const float* bo      = (const float*)d_in[12];
    const float* ln2_g   = (const float*)d_in[13];
    const float* ln2_b   = (const float*)d_in[14];
    const float* W1      = (const float*)d_in[15];
    const float* b1      = (const float*)d_in[16];
    const float* W2      = (const float*)d_in[17];
    const float* b2      = (const float*)d_in[18];
    const float* lnf_g   = (const float*)d_in[19];
    const float* lnf_b   = (const float*)d_in[20];
    const float* infW    = (const float*)d_in[21];

    // Workspace layout (exactly 5*BND*4 = 83,886,080 bytes):
    //   x      fp32  [M][D]          16,777,216 B
    //   h      bf16  [M][D]           8,388,608 B
    //   wts    bf16  (QKVt,WOt,W1t,W2t) 25,165,824 B
    //   big    union: {q/k/vt bf16 | ffh bf16 | hf fp32 + la/lb}
    char* wsb = (char*)d_ws;
    float*          x   = (float*)wsb;
    unsigned short* h   = (unsigned short*)(wsb + (size_t)BND * 4);
    unsigned short* wts = (unsigned short*)(wsb + (size_t)BND * 4 + (size_t)BND * 2);
    char*           big = wsb + (size_t)BND * 4 + (size_t)BND * 2 + 25165824;

    unsigned short* qbm = (unsigned short*)big;
    unsigned short* kbm = qbm + (size_t)M * D;
    unsigned short* vtm = kbm + (size_t)M * D;   // V^T: [b*512 + dcol][n]
    unsigned short* ffh = (unsigned short*)big;
    float*          hf  = (float*)big;
    float*          la  = hf + BND;
    float*          lb  = la + (size_t)M * C;

    unsigned short* QKVt = wts;                         // [L][3*D][D]
    unsigned short* WOt  = QKVt + (size_t)L * 3 * D * D;
    unsigned short* W1t  = WOt + (size_t)L * D * D;     // [L][DFF][D]
    unsigned short* W2t  = W1t + (size_t)L * D * DFF;   // [L][D][DFF]

    dim3 blk(256);

    // weight convert+transpose (per launch; ~30 us total)
    conv_t_kernel<<<dim3(D / 32, D / 32, L), blk, 0, stream>>>(Wq, QKVt,             D, D, 3 * D * D);
    conv_t_kernel<<<dim3(D / 32, D / 32, L), blk, 0, stream>>>(Wk, QKVt + D * D,     D, D, 3 * D * D);
    conv_t_kernel<<<dim3(D / 32, D / 32, L), blk, 0, stream>>>(Wv, QKVt + 2 * D * D, D, D, 3 * D * D);
    conv_t_kernel<<<dim3(D / 32, D / 32, L), blk, 0, stream>>>(Wo, WOt, D, D, D * D);
    conv_t_kernel<<<dim3(DFF / 32, D / 32, L), blk, 0, stream>>>(W1, W1t, D, DFF, D * DFF);
    conv_t_kernel<<<dim3(D / 32, DFF / 32, L), blk, 0, stream>>>(W2, W2t, DFF, D, DFF * D);

    embed_pe_kernel<<<BND / 256, blk, 0, stream>>>(src, emb, x);

    dim3 gqkv(3 * D / 128, M / 64);         // 12 x 128 = 1536 blocks
    dim3 gwo(D / 128, M / 64);              // 4 x 128 = 512 blocks
    dim3 gw1(DFF / 128, M / 64);            // 16 x 128 = 2048 blocks
    dim3 gw2(D / 128, M / 64);              // 4 x 128 = 512 blocks
    dim3 gattn(NSEQ / 64, H, B);            // 8 x 8 x 16

    for (int l = 0; l < L; l++) {
        size_t bd = (size_t)l * D;
        size_t wqkv = (size_t)l * 3 * D * D, wdd = (size_t)l * D * D;
        size_t wdf = (size_t)l * D * DFF, bf1 = (size_t)l * DFF;
        ln_kernel<1><<<M, blk, 0, stream>>>(x, ln1_g + bd, ln1_b + bd, h);
        mfma_gemm<3><<<gqkv, blk, 0, stream>>>(
            h, QKVt + wqkv, bq + bd, bk + bd, bv + bd, qbm, kbm, vtm, D, 3 * D);
        attn_mfma_kernel<<<gattn, blk, 0, stream>>>(qbm, kbm, vtm, lengths, h);
        mfma_gemm<0><<<gwo, blk, 0, stream>>>(
            h, WOt + wdd, bo + bd, nullptr, nullptr, x, nullptr, nullptr, D, D);
        ln_kernel<1><<<M, blk, 0, stream>>>(x, ln2_g + bd, ln2_b + bd, h);
        mfma_gemm<2><<<gw1, blk, 0, stream>>>(
            h, W1t + wdf, b1 + bf1, nullptr, nullptr, ffh, nullptr, nullptr, D, DFF);
        mfma_gemm<0><<<gw2, blk, 0, stream>>>(
            ffh, W2t + wdf, b2 + bd, nullptr, nullptr, x, nullptr, nullptr, DFF, D);
    }

    ln_kernel<0><<<M, blk, 0, stream>>>(x, lnf_g, lnf_b, hf);
    store_attnres<<<(NSEQ * B * D) / 256, blk, 0, stream>>>(hf, (float*)d_out);
    lalb_kernel<<<M, blk, 0, stream>>>(hf, infW, la, lb);
    logits_kernel<<<(NSEQ * NSEQ * B) / 256, blk, 0, stream>>>(
        la, lb, (float*)d_out + (size_t)NSEQ * B * D);
}